// Round 9
// baseline (227.723 us; speedup 1.0000x reference)
//
#include <hip/hip_runtime.h>

typedef _Float16 f16;
typedef f16 f16x8 __attribute__((ext_vector_type(8)));
typedef float f32x16 __attribute__((ext_vector_type(16)));

#define LSCALE 2048.0f          // lo-parts stored *2^11 (exact) to avoid f16 denormals
#define LINV   4.8828125e-4f    // 2^-11
#define XS 136                  // LDS row stride in halfs: 16B-aligned b128 rows, bank-floor access

#define MFMA32(A,B,C) __builtin_amdgcn_mfma_f32_32x32x16_f16(A, B, C, 0, 0, 0)

// ---------------------------------------------------------------------------
// Kernel 0: replicate the reference's fp32 cas table EXACTLY (round-2 lesson:
// a more accurate table FAILS), then split-fp16 tables A=cas, V[f][m]=cas[f][127-m].
// ---------------------------------------------------------------------------
__global__ void k_cas(float* __restrict__ casf,
                      f16* __restrict__ Ah, f16* __restrict__ Al,
                      f16* __restrict__ Vh, f16* __restrict__ Vl) {
    int f = blockIdx.x, m = threadIdx.x;
    const float SC = (float)(6.283185307179586 / 128.0);  // fp32(2*pi/128)
    float ang = SC * (float)(f * m);                      // fp32, unreduced
    double a = (double)ang;
    float v = (float)cos(a) + (float)sin(a);
    casf[f * 128 + m] = v;
    f16 h = (f16)v;
    f16 lo = (f16)((v - (float)h) * LSCALE);
    Ah[f * 128 + m] = h;
    Al[f * 128 + m] = lo;
    Vh[f * 128 + 127 - m] = h;
    Vl[f * 128 + 127 - m] = lo;
}

// ---------------------------------------------------------------------------
// Kernel 1 (32x32x16 MFMA, 16 waves): per image:
//   pass1: wave (gt1=wv>>2, mt1=wv&3) computes 32x32 tiles of
//          W1[g,m]=sum_n A[g,n]X[m,n] and W2[g,m]=sum_n V[g,n]X[m,n]
//   pass2: wave (ft=wv>>2, gt=wv&3) computes BOTH C[f,g]=sum_m A[f,m]W1[g,m]
//          and S[f,g]=sum_m V[f,m]W2[g,m] -> in-register cosphi pairing.
// 32x32 shape: 2x FLOP per LDS byte vs 16x16x32 -> DS reads halve (bytes),
// 4x fewer ds_read instrs (single b128/operand), MFMA instrs halve.
// C/D layout col=lane&31, row=(reg&3)+8(reg>>2)+4(lane>>5) [HW-verified];
// A/B k-mapping k=16ks+8*(lane>>5)+e used consistently on both operands
// (bijection argument -> exact for any HW k-permutation; validated round 7).
// ---------------------------------------------------------------------------
__global__ __launch_bounds__(1024) void k_dht(
    const float* __restrict__ xg,
    const f16* __restrict__ Ah, const f16* __restrict__ Al,
    const f16* __restrict__ Vh, const f16* __restrict__ Vl,
    float* __restrict__ outbuf,
    float* __restrict__ cp1, float* __restrict__ cp2)
{
    __shared__ __align__(16) char smem[139264];
    f16* Xh  = (f16*)smem;               // [128][XS]
    f16* Xl  = (f16*)(smem + 34816);
    f16* W1h = (f16*)smem;               // reuse X region after pass 1
    f16* W1l = (f16*)(smem + 34816);
    f16* W2h = (f16*)(smem + 69632);
    f16* W2l = (f16*)(smem + 104448);

    const int img = blockIdx.x;
    const float* X = xg + (size_t)img * 16384;
    const int t = threadIdx.x;
    const int lane = t & 63;
    const int wv = t >> 6;               // 0..15
    const int l31 = lane & 31;
    const int hh  = lane >> 5;           // 0/1
    const int koff = 8 * hh;

    // ---- stage X -> split fp16 planes in LDS (b128 writes) ----
    #pragma unroll
    for (int c = 0; c < 2; ++c) {
        int j = c * 1024 + t;            // 8-float chunk index 0..2047
        int r = j >> 4, c8 = (j & 15) * 8;
        float4 xa = *(const float4*)&X[r * 128 + c8];
        float4 xb = *(const float4*)&X[r * 128 + c8 + 4];
        const float* xp = (const float*)&xa;
        const float* xq = (const float*)&xb;
        f16x8 hv, lv;
        #pragma unroll
        for (int u = 0; u < 4; ++u) {
            f16 h = (f16)xp[u];
            hv[u] = h; lv[u] = (f16)((xp[u] - (float)h) * LSCALE);
            f16 h2 = (f16)xq[u];
            hv[u + 4] = h2; lv[u + 4] = (f16)((xq[u] - (float)h2) * LSCALE);
        }
        *(f16x8*)&Xh[r * XS + c8] = hv;
        *(f16x8*)&Xl[r * XS + c8] = lv;
    }
    __syncthreads();

    // ---- pass 1: W1/W2 tile (gt1, mt1) ----
    const int gt1 = wv >> 2, mt1 = wv & 3;
    f32x16 w1hi, w1lo, w2hi, w2lo;
    #pragma unroll
    for (int i = 0; i < 16; ++i) { w1hi[i]=0.f; w1lo[i]=0.f; w2hi[i]=0.f; w2lo[i]=0.f; }
    {
        const int arow = (gt1 * 32 + l31) * 128;
        const int brow = (mt1 * 32 + l31) * XS;
        #pragma unroll 1
        for (int ks = 0; ks < 8; ++ks) {
            const int ta = arow + ks * 16 + koff;
            f16x8 tah = *(const f16x8*)&Ah[ta];
            f16x8 tal = *(const f16x8*)&Al[ta];
            f16x8 tvh = *(const f16x8*)&Vh[ta];
            f16x8 tvl = *(const f16x8*)&Vl[ta];
            const int xb = brow + ks * 16 + koff;
            f16x8 xh = *(const f16x8*)&Xh[xb];
            f16x8 xl = *(const f16x8*)&Xl[xb];
            w1hi = MFMA32(tah, xh, w1hi);
            w1lo = MFMA32(tal, xh, w1lo);
            w1lo = MFMA32(tah, xl, w1lo);
            w2hi = MFMA32(tvh, xh, w2hi);
            w2lo = MFMA32(tvl, xh, w2lo);
            w2lo = MFMA32(tvh, xl, w2lo);
        }
    }
    __syncthreads();   // X reads done before W1 overwrites X region

    // ---- combine + split W into f16 h/l planes ----
    {
        const int m = mt1 * 32 + l31;
        #pragma unroll
        for (int r = 0; r < 16; ++r) {
            const int g = gt1 * 32 + (r & 3) + 8 * (r >> 2) + 4 * hh;
            float v1 = w1hi[r] + LINV * w1lo[r];
            f16 h1 = (f16)v1;
            float v2 = w2hi[r] + LINV * w2lo[r];
            f16 h2 = (f16)v2;
            W1h[g * XS + m] = h1;
            W1l[g * XS + m] = (f16)((v1 - (float)h1) * LSCALE);
            W2h[g * XS + m] = h2;
            W2l[g * XS + m] = (f16)((v2 - (float)h2) * LSCALE);
        }
    }
    __syncthreads();

    // ---- pass 2: C and S tile (ft, gt), paired in-register ----
    const int ft = wv >> 2, gt = wv & 3;
    f32x16 chi, clo, shi, slo;
    #pragma unroll
    for (int i = 0; i < 16; ++i) { chi[i]=0.f; clo[i]=0.f; shi[i]=0.f; slo[i]=0.f; }
    {
        const int frow = (ft * 32 + l31) * 128;
        const int grow = (gt * 32 + l31) * XS;
        #pragma unroll 1
        for (int ms = 0; ms < 8; ++ms) {
            const int ta = frow + ms * 16 + koff;
            f16x8 tah = *(const f16x8*)&Ah[ta];
            f16x8 tal = *(const f16x8*)&Al[ta];
            f16x8 tvh = *(const f16x8*)&Vh[ta];
            f16x8 tvl = *(const f16x8*)&Vl[ta];
            const int wb = grow + ms * 16 + koff;
            f16x8 u1h = *(const f16x8*)&W1h[wb];
            f16x8 u1l = *(const f16x8*)&W1l[wb];
            f16x8 u2h = *(const f16x8*)&W2h[wb];
            f16x8 u2l = *(const f16x8*)&W2l[wb];
            chi = MFMA32(tah, u1h, chi);
            clo = MFMA32(tal, u1h, clo);
            clo = MFMA32(tah, u1l, clo);
            shi = MFMA32(tvh, u2h, shi);
            slo = MFMA32(tvl, u2h, slo);
            slo = MFMA32(tvh, u2l, slo);
        }
    }

    // ---- epilogue: cosphi (f16, packed into out) + corners, in-register ----
    f16* cph = (f16*)(outbuf + (size_t)img * 16384);
    const int g = gt * 32 + l31;
    #pragma unroll
    for (int r = 0; r < 16; ++r) {
        const int f = ft * 32 + (r & 3) + 8 * (r >> 2) + 4 * hh;
        float Cv = chi[r] + LINV * clo[r];
        float Sv = shi[r] + LINV * slo[r];
        float d = Cv * Cv + Sv * Sv;
        float cp = (d > 0.f) ? Cv * rsqrtf(d) : 1.0f;
        cph[f * 128 + g] = (f16)cp;
        if (gt == 0 && l31 < 16) {
            if (ft == 0 && (r >> 2) < 2)
                cp1[img * 256 + f * 16 + l31] = Cv;          // f in 0..15
            else if (ft == 3 && (r >> 2) >= 2)
                cp2[img * 256 + (f - 112) * 16 + l31] = Cv;  // f in 112..127
        }
    }
}

// ---------------------------------------------------------------------------
// Kernel 2: corner complex-mul.  od[b,o,x,y] = 0.5*sum_i(A*(W+Wn)+An*(W-Wn))
// ---------------------------------------------------------------------------
__global__ __launch_bounds__(256) void k_corner(
    const float* __restrict__ cp1, const float* __restrict__ cp2,
    const float* __restrict__ w1,  const float* __restrict__ w2,
    float* __restrict__ od1, float* __restrict__ od2)
{
    const int c = blockIdx.y;
    const float* cp = c ? cp2 : cp1;
    const float* w  = c ? w2  : w1;
    float* od       = c ? od2 : od1;
    const int b = blockIdx.x >> 6, o = blockIdx.x & 63;
    const int t = threadIdx.x;
    const int xx = t >> 4, yy = t & 15;
    const int nx = (16 - xx) & 15, ny = (16 - yy) & 15;

    float acc = 0.f;
    #pragma unroll 4
    for (int i = 0; i < 64; ++i) {
        float A  = cp[((b * 64 + i) * 16 + xx) * 16 + yy];
        float An = cp[((b * 64 + i) * 16 + nx) * 16 + ny];
        float W  = w[((i * 64 + o) * 16 + xx) * 16 + yy];
        float Wn = w[((i * 64 + o) * 16 + nx) * 16 + ny];
        acc += A * (W + Wn) + An * (W - Wn);
    }
    od[((b * 64 + o) * 16 + xx) * 16 + yy] = 0.5f * acc;
}

// ---------------------------------------------------------------------------
// Kernel 3: sparse inverse DHT + final multiply.  cosphi arrives as f16 packed
// in out's first 32KB per image; staged to LDS, then out overwritten in-place.
// ---------------------------------------------------------------------------
__global__ __launch_bounds__(256) void k_inv(
    const float* __restrict__ od1, const float* __restrict__ od2,
    const float* __restrict__ cas,
    float* __restrict__ out)
{
    __shared__ float odS[32 * 16];
    __shared__ float casF[128 * 33];
    __shared__ float Rs[128 * 17];
    __shared__ float casG[16 * 128];
    __shared__ __align__(16) unsigned short cphS[16384];   // 32KB

    const int img = blockIdx.x;
    const int t = threadIdx.x;

    const uint4* cp16 = (const uint4*)(out + (size_t)img * 16384);
    #pragma unroll
    for (int k = 0; k < 8; ++k) {
        int i = k * 256 + t;
        ((uint4*)cphS)[i] = cp16[i];
    }

    odS[t]       = od1[img * 256 + t];
    odS[256 + t] = od2[img * 256 + t];
    #pragma unroll
    for (int k = 0; k < 16; ++k) {
        int idx = t + k * 256;
        int s = idx >> 5, j = idx & 31;
        int f = (j < 16) ? j : (96 + j);
        casF[s * 33 + j] = cas[s * 128 + f];
    }
    #pragma unroll
    for (int k = 0; k < 8; ++k) {
        int idx = t + k * 256;
        casG[idx] = cas[idx];
    }
    __syncthreads();

    {
        const int s1 = t >> 1, gb = (t & 1) * 8;
        float acc[8];
        #pragma unroll
        for (int l = 0; l < 8; ++l) acc[l] = 0.f;
        #pragma unroll 4
        for (int j = 0; j < 32; ++j) {
            float cf = casF[s1 * 33 + j];
            #pragma unroll
            for (int l = 0; l < 8; ++l)
                acc[l] = fmaf(cf, odS[j * 16 + gb + l], acc[l]);
        }
        #pragma unroll
        for (int l = 0; l < 8; ++l) Rs[s1 * 17 + gb + l] = acc[l];
    }
    __syncthreads();

    const float inv = 1.0f / 16384.0f;
    const int grp = t >> 5, lane = t & 31;
    const int s2 = lane * 4;
    for (int r = 0; r < 16; ++r) {
        const int s1 = grp * 16 + r;
        float4 acc = {0.f, 0.f, 0.f, 0.f};
        #pragma unroll
        for (int g = 0; g < 16; ++g) {
            float rv = Rs[s1 * 17 + g];
            float4 c4 = *(const float4*)&casG[g * 128 + s2];
            acc.x = fmaf(rv, c4.x, acc.x);
            acc.y = fmaf(rv, c4.y, acc.y);
            acc.z = fmaf(rv, c4.z, acc.z);
            acc.w = fmaf(rv, c4.w, acc.w);
        }
        const f16* ph = (const f16*)cphS + s1 * 128 + s2;
        size_t idx = (size_t)img * 16384 + (size_t)s1 * 128 + s2;
        float4 res;
        res.x = acc.x * inv * (float)ph[0];
        res.y = acc.y * inv * (float)ph[1];
        res.z = acc.z * inv * (float)ph[2];
        res.w = acc.w * inv * (float)ph[3];
        *(float4*)&out[idx] = res;
    }
}

// ---------------------------------------------------------------------------
extern "C" void kernel_launch(void* const* d_in, const int* in_sizes, int n_in,
                              void* d_out, int out_size, void* d_ws, size_t ws_size,
                              hipStream_t stream) {
    (void)in_sizes; (void)n_in; (void)out_size; (void)ws_size;
    const float* x  = (const float*)d_in[0];
    const float* w1 = (const float*)d_in[1];
    const float* w2 = (const float*)d_in[2];
    float* out = (float*)d_out;
    float* ws  = (float*)d_ws;

    float* casf = ws;                        // 16384 f32
    f16* Ah = (f16*)(ws + 16384);            // 16384 halfs each
    f16* Al = Ah + 16384;
    f16* Vh = Al + 16384;
    f16* Vl = Vh + 16384;
    float* cp1 = (float*)(Vl + 16384);       // 262144 f32 each
    float* cp2 = cp1 + 262144;
    float* od1 = cp2 + 262144;
    float* od2 = od1 + 262144;               // total ~4.4 MB

    k_cas<<<dim3(128), dim3(128), 0, stream>>>(casf, Ah, Al, Vh, Vl);
    k_dht<<<dim3(1024), dim3(1024), 0, stream>>>(x, Ah, Al, Vh, Vl, out, cp1, cp2);
    k_corner<<<dim3(1024, 2), dim3(256), 0, stream>>>(cp1, cp2, w1, w2, od1, od2);
    k_inv<<<dim3(1024), dim3(256), 0, stream>>>(od1, od2, casf, out);
}

// Round 10
// 148.509 us; speedup vs baseline: 1.5334x; 1.5334x over previous
//
#include <hip/hip_runtime.h>

typedef _Float16 f16;
typedef f16 f16x8 __attribute__((ext_vector_type(8)));
typedef float f32x4 __attribute__((ext_vector_type(4)));

#define LSCALE 2048.0f          // lo-parts stored *2^11 (exact) to avoid f16 denormals
#define LINV   4.8828125e-4f    // 2^-11
#define XS 136                  // LDS row stride in halfs (272B = 16*17): b128-aligned rows

#define MFMA(A,B,C) __builtin_amdgcn_mfma_f32_16x16x32_f16(A, B, C, 0, 0, 0)

// ---------------------------------------------------------------------------
// Kernel 0: replicate the reference's fp32 cas table EXACTLY (round-2 lesson:
// a more accurate table FAILS), then write split-f16 tables A=cas and
// V[f][m]=cas[f][127-m] in MFMA-FRAGMENT ORDER:
//   slot(row,k) = ((row>>4)*4 + (k>>5))*64 + ((k>>3)&3)*16 + (row&15), 8 halfs
// so a wave's fragment load is base + lane*16B -> ONE coalesced transaction
// (round-9 lesson: row-major table frag loads are 32-line gathers that stall).
// ---------------------------------------------------------------------------
__device__ __forceinline__ int frag_slot(int row, int k) {
    return ((((row >> 4) * 4 + (k >> 5)) * 64) + ((k >> 3) & 3) * 16 + (row & 15)) * 8 + (k & 7);
}

__global__ void k_cas(float* __restrict__ casf,
                      f16* __restrict__ FAh, f16* __restrict__ FAl,
                      f16* __restrict__ FVh, f16* __restrict__ FVl) {
    int f = blockIdx.x, m = threadIdx.x;
    const float SC = (float)(6.283185307179586 / 128.0);  // fp32(2*pi/128)
    float ang = SC * (float)(f * m);                      // fp32, unreduced
    double a = (double)ang;
    float v = (float)cos(a) + (float)sin(a);
    casf[f * 128 + m] = v;
    f16 h = (f16)v;
    f16 lo = (f16)((v - (float)h) * LSCALE);
    int sA = frag_slot(f, m);
    FAh[sA] = h;
    FAl[sA] = lo;
    int sV = frag_slot(f, 127 - m);    // V[f][127-m] = cas[f][m]
    FVh[sV] = h;
    FVl[sV] = lo;
}

// ---------------------------------------------------------------------------
// Kernel 1 (16x16x32 MFMA, 16 waves; round-8 structure + coalesced frag tables):
//   pass1: wave (gw=wv&7, mh=(wv>>3)*4): W1[g,m]=sum_n A[g,n]X[m,n], W2 from V
//   pass2: wave (ft=wv>>1, gh=wv&1): C[f,g]=sum_m A[f,m]W1[g,m] and
//          S[f,g]=sum_m V[f,m]W2[g,m] -> in-register cosphi pairing.
// Split-fp16: P*Q = Ph*Qh + 2^-11*(Pl'*Qh + Ph*Ql'). Same MFMA order as
// round 8 -> bitwise-identical output (absmax 3.814697e-06).
// ---------------------------------------------------------------------------
__global__ __launch_bounds__(1024) void k_dht(
    const float* __restrict__ xg,
    const f16* __restrict__ FAh, const f16* __restrict__ FAl,
    const f16* __restrict__ FVh, const f16* __restrict__ FVl,
    float* __restrict__ outbuf,
    float* __restrict__ cp1, float* __restrict__ cp2)
{
    __shared__ __align__(16) char smem[143360];
    f16* Xh  = (f16*)smem;               // [128][XS]
    f16* Xl  = (f16*)(smem + 35840);
    f16* W1h = (f16*)smem;               // reuse X region after pass 1
    f16* W1l = (f16*)(smem + 35840);
    f16* W2h = (f16*)(smem + 71680);
    f16* W2l = (f16*)(smem + 107520);

    const int img = blockIdx.x;
    const float* X = xg + (size_t)img * 16384;
    const int t = threadIdx.x;
    const int lane = t & 63;
    const int wv = t >> 6;               // 0..15
    const int l15 = lane & 15;
    const int a4 = lane >> 4;            // 0..3

    // ---- stage X -> split fp16 planes in LDS ----
    #pragma unroll
    for (int it = 0; it < 4; ++it) {
        int i = it * 1024 + t;           // float4 index 0..4095
        int r = i >> 5, c0 = (i & 31) * 4;
        float4 xv = *(const float4*)&X[r * 128 + c0];
        const float* xp = (const float*)&xv;
        #pragma unroll
        for (int j = 0; j < 4; ++j) {
            f16 h = (f16)xp[j];
            Xh[r * XS + c0 + j] = h;
            Xl[r * XS + c0 + j] = (f16)((xp[j] - (float)h) * LSCALE);
        }
    }
    __syncthreads();

    // ---- pass 1: wave -> (gtile gw, m-half mh), computes W1 and W2 tiles ----
    const int gw = wv & 7;
    const int mh = (wv >> 3) * 4;
    f32x4 w1hi[4], w1lo[4], w2hi[4], w2lo[4];
    #pragma unroll
    for (int i = 0; i < 4; ++i) {
        w1hi[i] = (f32x4){0.f,0.f,0.f,0.f}; w1lo[i] = (f32x4){0.f,0.f,0.f,0.f};
        w2hi[i] = (f32x4){0.f,0.f,0.f,0.f}; w2lo[i] = (f32x4){0.f,0.f,0.f,0.f};
    }
    {
        #pragma unroll 1
        for (int ks = 0; ks < 4; ++ks) {
            const int toff = ((gw * 4 + ks) * 64 + lane) * 8;   // coalesced frag
            f16x8 tah = *(const f16x8*)&FAh[toff];
            f16x8 tal = *(const f16x8*)&FAl[toff];
            f16x8 tvh = *(const f16x8*)&FVh[toff];
            f16x8 tvl = *(const f16x8*)&FVl[toff];
            #pragma unroll
            for (int mi = 0; mi < 4; ++mi) {
                const int base = (16 * (mh + mi) + l15) * XS + ks * 32 + 8 * a4;
                f16x8 xh = *(const f16x8*)&Xh[base];            // aligned b128
                f16x8 xl = *(const f16x8*)&Xl[base];
                w1hi[mi] = MFMA(tah, xh, w1hi[mi]);
                w1lo[mi] = MFMA(tal, xh, w1lo[mi]);
                w1lo[mi] = MFMA(tah, xl, w1lo[mi]);
                w2hi[mi] = MFMA(tvh, xh, w2hi[mi]);
                w2lo[mi] = MFMA(tvl, xh, w2lo[mi]);
                w2lo[mi] = MFMA(tvh, xl, w2lo[mi]);
            }
        }
    }
    __syncthreads();

    // ---- combine + split W into f16 h/l planes (W1 over X region) ----
    {
        const int g = 16 * gw + 4 * a4;
        #pragma unroll
        for (int mi = 0; mi < 4; ++mi) {
            const int m = 16 * (mh + mi) + l15;
            #pragma unroll
            for (int r = 0; r < 4; ++r) {
                float v1 = w1hi[mi][r] + LINV * w1lo[mi][r];
                f16 h1 = (f16)v1;
                float v2 = w2hi[mi][r] + LINV * w2lo[mi][r];
                f16 h2 = (f16)v2;
                W2h[(g + r) * XS + m] = h2;
                W2l[(g + r) * XS + m] = (f16)((v2 - (float)h2) * LSCALE);
                W1h[(g + r) * XS + m] = h1;
                W1l[(g + r) * XS + m] = (f16)((v1 - (float)h1) * LSCALE);
            }
        }
    }
    __syncthreads();

    // ---- pass 2: wave (ft = wv>>1, ghalf = wv&1): C and S paired ----
    const int ft = wv >> 1;
    const int gh = wv & 1;
    f32x4 chi[4], clo[4], shi[4], slo[4];
    #pragma unroll
    for (int i = 0; i < 4; ++i) {
        chi[i] = (f32x4){0.f,0.f,0.f,0.f}; clo[i] = (f32x4){0.f,0.f,0.f,0.f};
        shi[i] = (f32x4){0.f,0.f,0.f,0.f}; slo[i] = (f32x4){0.f,0.f,0.f,0.f};
    }
    {
        #pragma unroll 1
        for (int ks = 0; ks < 4; ++ks) {
            const int toff = ((ft * 4 + ks) * 64 + lane) * 8;   // coalesced frag
            f16x8 tah = *(const f16x8*)&FAh[toff];
            f16x8 tal = *(const f16x8*)&FAl[toff];
            f16x8 tvh = *(const f16x8*)&FVh[toff];
            f16x8 tvl = *(const f16x8*)&FVl[toff];
            #pragma unroll
            for (int gi = 0; gi < 4; ++gi) {
                const int gt = 4 * gh + gi;
                const int base = (16 * gt + l15) * XS + ks * 32 + 8 * a4;
                f16x8 u1h = *(const f16x8*)&W1h[base];
                f16x8 u1l = *(const f16x8*)&W1l[base];
                f16x8 u2h = *(const f16x8*)&W2h[base];
                f16x8 u2l = *(const f16x8*)&W2l[base];
                chi[gi] = MFMA(tah, u1h, chi[gi]);
                clo[gi] = MFMA(tal, u1h, clo[gi]);
                clo[gi] = MFMA(tah, u1l, clo[gi]);
                shi[gi] = MFMA(tvh, u2h, shi[gi]);
                slo[gi] = MFMA(tvl, u2h, slo[gi]);
                slo[gi] = MFMA(tvh, u2l, slo[gi]);
            }
        }
    }

    // ---- epilogue: cosphi (f16, packed into out) + corners, in-register ----
    f16* cph = (f16*)(outbuf + (size_t)img * 16384);
    #pragma unroll
    for (int gi = 0; gi < 4; ++gi) {
        const int g = 16 * (4 * gh + gi) + l15;
        #pragma unroll
        for (int r = 0; r < 4; ++r) {
            const int f = 16 * ft + 4 * a4 + r;
            float Cv = chi[gi][r] + LINV * clo[gi][r];
            float Sv = shi[gi][r] + LINV * slo[gi][r];
            float d = Cv * Cv + Sv * Sv;
            float cp = (d > 0.f) ? Cv * rsqrtf(d) : 1.0f;
            cph[f * 128 + g] = (f16)cp;
            if (gh == 0 && gi == 0) {
                if (ft == 0)      cp1[img * 256 + f * 16 + l15] = Cv;
                else if (ft == 7) cp2[img * 256 + (f - 112) * 16 + l15] = Cv;
            }
        }
    }
}

// ---------------------------------------------------------------------------
// Kernel 2: corner complex-mul.  od[b,o,x,y] = 0.5*sum_i(A*(W+Wn)+An*(W-Wn))
// ---------------------------------------------------------------------------
__global__ __launch_bounds__(256) void k_corner(
    const float* __restrict__ cp1, const float* __restrict__ cp2,
    const float* __restrict__ w1,  const float* __restrict__ w2,
    float* __restrict__ od1, float* __restrict__ od2)
{
    const int c = blockIdx.y;
    const float* cp = c ? cp2 : cp1;
    const float* w  = c ? w2  : w1;
    float* od       = c ? od2 : od1;
    const int b = blockIdx.x >> 6, o = blockIdx.x & 63;
    const int t = threadIdx.x;
    const int xx = t >> 4, yy = t & 15;
    const int nx = (16 - xx) & 15, ny = (16 - yy) & 15;

    float acc = 0.f;
    #pragma unroll 4
    for (int i = 0; i < 64; ++i) {
        float A  = cp[((b * 64 + i) * 16 + xx) * 16 + yy];
        float An = cp[((b * 64 + i) * 16 + nx) * 16 + ny];
        float W  = w[((i * 64 + o) * 16 + xx) * 16 + yy];
        float Wn = w[((i * 64 + o) * 16 + nx) * 16 + ny];
        acc += A * (W + Wn) + An * (W - Wn);
    }
    od[((b * 64 + o) * 16 + xx) * 16 + yy] = 0.5f * acc;
}

// ---------------------------------------------------------------------------
// Kernel 3: sparse inverse DHT + final multiply.  cosphi arrives as f16 packed
// in out's first 32KB per image; staged to LDS, then out overwritten in-place.
// ---------------------------------------------------------------------------
__global__ __launch_bounds__(256) void k_inv(
    const float* __restrict__ od1, const float* __restrict__ od2,
    const float* __restrict__ cas,
    float* __restrict__ out)
{
    __shared__ float odS[32 * 16];
    __shared__ float casF[128 * 33];
    __shared__ float Rs[128 * 17];
    __shared__ float casG[16 * 128];
    __shared__ __align__(16) unsigned short cphS[16384];   // 32KB

    const int img = blockIdx.x;
    const int t = threadIdx.x;

    const uint4* cp16 = (const uint4*)(out + (size_t)img * 16384);
    #pragma unroll
    for (int k = 0; k < 8; ++k) {
        int i = k * 256 + t;
        ((uint4*)cphS)[i] = cp16[i];
    }

    odS[t]       = od1[img * 256 + t];
    odS[256 + t] = od2[img * 256 + t];
    #pragma unroll
    for (int k = 0; k < 16; ++k) {
        int idx = t + k * 256;
        int s = idx >> 5, j = idx & 31;
        int f = (j < 16) ? j : (96 + j);
        casF[s * 33 + j] = cas[s * 128 + f];
    }
    #pragma unroll
    for (int k = 0; k < 8; ++k) {
        int idx = t + k * 256;
        casG[idx] = cas[idx];
    }
    __syncthreads();

    {
        const int s1 = t >> 1, gb = (t & 1) * 8;
        float acc[8];
        #pragma unroll
        for (int l = 0; l < 8; ++l) acc[l] = 0.f;
        #pragma unroll 4
        for (int j = 0; j < 32; ++j) {
            float cf = casF[s1 * 33 + j];
            #pragma unroll
            for (int l = 0; l < 8; ++l)
                acc[l] = fmaf(cf, odS[j * 16 + gb + l], acc[l]);
        }
        #pragma unroll
        for (int l = 0; l < 8; ++l) Rs[s1 * 17 + gb + l] = acc[l];
    }
    __syncthreads();

    const float inv = 1.0f / 16384.0f;
    const int grp = t >> 5, lane = t & 31;
    const int s2 = lane * 4;
    for (int r = 0; r < 16; ++r) {
        const int s1 = grp * 16 + r;
        float4 acc = {0.f, 0.f, 0.f, 0.f};
        #pragma unroll
        for (int g = 0; g < 16; ++g) {
            float rv = Rs[s1 * 17 + g];
            float4 c4 = *(const float4*)&casG[g * 128 + s2];
            acc.x = fmaf(rv, c4.x, acc.x);
            acc.y = fmaf(rv, c4.y, acc.y);
            acc.z = fmaf(rv, c4.z, acc.z);
            acc.w = fmaf(rv, c4.w, acc.w);
        }
        const f16* ph = (const f16*)cphS + s1 * 128 + s2;
        size_t idx = (size_t)img * 16384 + (size_t)s1 * 128 + s2;
        float4 res;
        res.x = acc.x * inv * (float)ph[0];
        res.y = acc.y * inv * (float)ph[1];
        res.z = acc.z * inv * (float)ph[2];
        res.w = acc.w * inv * (float)ph[3];
        *(float4*)&out[idx] = res;
    }
}

// ---------------------------------------------------------------------------
extern "C" void kernel_launch(void* const* d_in, const int* in_sizes, int n_in,
                              void* d_out, int out_size, void* d_ws, size_t ws_size,
                              hipStream_t stream) {
    (void)in_sizes; (void)n_in; (void)out_size; (void)ws_size;
    const float* x  = (const float*)d_in[0];
    const float* w1 = (const float*)d_in[1];
    const float* w2 = (const float*)d_in[2];
    float* out = (float*)d_out;
    float* ws  = (float*)d_ws;

    float* casf = ws;                        // 16384 f32
    f16* FAh = (f16*)(ws + 16384);           // 16384 halfs each, frag-ordered
    f16* FAl = FAh + 16384;
    f16* FVh = FAl + 16384;
    f16* FVl = FVh + 16384;
    float* cp1 = (float*)(FVl + 16384);      // 262144 f32 each
    float* cp2 = cp1 + 262144;
    float* od1 = cp2 + 262144;
    float* od2 = od1 + 262144;               // total ~4.4 MB

    k_cas<<<dim3(128), dim3(128), 0, stream>>>(casf, FAh, FAl, FVh, FVl);
    k_dht<<<dim3(1024), dim3(1024), 0, stream>>>(x, FAh, FAl, FVh, FVl, out, cp1, cp2);
    k_corner<<<dim3(1024, 2), dim3(256), 0, stream>>>(cp1, cp2, w1, w2, od1, od2);
    k_inv<<<dim3(1024), dim3(256), 0, stream>>>(od1, od2, casf, out);
}

// Round 11
// 139.703 us; speedup vs baseline: 1.6300x; 1.0630x over previous
//
#include <hip/hip_runtime.h>

typedef _Float16 f16;
typedef f16 f16x4 __attribute__((ext_vector_type(4)));
typedef f16 f16x8 __attribute__((ext_vector_type(8)));
typedef float f32x4 __attribute__((ext_vector_type(4)));

#define LSCALE 2048.0f          // lo-parts stored *2^11 (exact) to avoid f16 denormals
#define LINV   4.8828125e-4f    // 2^-11
#define XS 136                  // LDS row stride in halfs (272B): b128-aligned rows, 2-way reads

#define MFMA(A,B,C) __builtin_amdgcn_mfma_f32_16x16x32_f16(A, B, C, 0, 0, 0)

// ---------------------------------------------------------------------------
// Kernel 0: replicate the reference's fp32 cas table EXACTLY (round-2 lesson:
// a more accurate table FAILS), then write split-f16 tables A=cas and
// V[f][m]=cas[f][127-m] in MFMA-FRAGMENT ORDER (round-10 lesson: row-major
// fragment loads are 32-line gathers; frag order -> one coalesced transaction).
// ---------------------------------------------------------------------------
__device__ __forceinline__ int frag_slot(int row, int k) {
    return ((((row >> 4) * 4 + (k >> 5)) * 64) + ((k >> 3) & 3) * 16 + (row & 15)) * 8 + (k & 7);
}

__global__ void k_cas(float* __restrict__ casf,
                      f16* __restrict__ FAh, f16* __restrict__ FAl,
                      f16* __restrict__ FVh, f16* __restrict__ FVl) {
    int f = blockIdx.x, m = threadIdx.x;
    const float SC = (float)(6.283185307179586 / 128.0);  // fp32(2*pi/128)
    float ang = SC * (float)(f * m);                      // fp32, unreduced
    double a = (double)ang;
    float v = (float)cos(a) + (float)sin(a);
    casf[f * 128 + m] = v;
    f16 h = (f16)v;
    f16 lo = (f16)((v - (float)h) * LSCALE);
    int sA = frag_slot(f, m);
    FAh[sA] = h;
    FAl[sA] = lo;
    int sV = frag_slot(f, 127 - m);    // V[f][127-m] = cas[f][m]
    FVh[sV] = h;
    FVl[sV] = lo;
}

// ---------------------------------------------------------------------------
// Kernel 1 (16x16x32 MFMA, 16 waves; round-10 structure, b64 staging writes):
//   pass1: wave (gw=wv&7, mh=(wv>>3)*4): W1[g,m]=sum_n A[g,n]X[m,n], W2 from V
//   pass2: wave (ft=wv>>1, gh=wv&1): C[f,g]=sum_m A[f,m]W1[g,m] and
//          S[f,g]=sum_m V[f,m]W2[g,m] -> in-register cosphi pairing.
// Split-fp16: P*Q = Ph*Qh + 2^-11*(Pl'*Qh + Ph*Ql').  Same MFMA order since
// round 8 -> bitwise-identical output (absmax 3.814697e-06).
// ---------------------------------------------------------------------------
__global__ __launch_bounds__(1024) void k_dht(
    const float* __restrict__ xg,
    const f16* __restrict__ FAh, const f16* __restrict__ FAl,
    const f16* __restrict__ FVh, const f16* __restrict__ FVl,
    float* __restrict__ outbuf,
    float* __restrict__ cp1, float* __restrict__ cp2)
{
    __shared__ __align__(16) char smem[143360];
    f16* Xh  = (f16*)smem;               // [128][XS]
    f16* Xl  = (f16*)(smem + 35840);
    f16* W1h = (f16*)smem;               // reuse X region after pass 1
    f16* W1l = (f16*)(smem + 35840);
    f16* W2h = (f16*)(smem + 71680);
    f16* W2l = (f16*)(smem + 107520);

    const int img = blockIdx.x;
    const float* X = xg + (size_t)img * 16384;
    const int t = threadIdx.x;
    const int lane = t & 63;
    const int wv = t >> 6;               // 0..15
    const int l15 = lane & 15;
    const int a4 = lane >> 4;            // 0..3

    // ---- stage X -> split fp16 planes in LDS (b64 vector writes, round-8
    //      pattern: scalar b16 staging writes cost 6.3M bank conflicts) ----
    #pragma unroll
    for (int it = 0; it < 4; ++it) {
        int i = it * 1024 + t;           // float4 index 0..4095
        int r = i >> 5, c0 = (i & 31) * 4;
        float4 xv = *(const float4*)&X[r * 128 + c0];
        const float* xp = (const float*)&xv;
        f16x4 hv, lv;
        #pragma unroll
        for (int j = 0; j < 4; ++j) {
            f16 h = (f16)xp[j];
            hv[j] = h;
            lv[j] = (f16)((xp[j] - (float)h) * LSCALE);
        }
        *(f16x4*)&Xh[r * XS + c0] = hv;
        *(f16x4*)&Xl[r * XS + c0] = lv;
    }
    __syncthreads();

    // ---- pass 1: wave -> (gtile gw, m-half mh), computes W1 and W2 tiles ----
    const int gw = wv & 7;
    const int mh = (wv >> 3) * 4;
    f32x4 w1hi[4], w1lo[4], w2hi[4], w2lo[4];
    #pragma unroll
    for (int i = 0; i < 4; ++i) {
        w1hi[i] = (f32x4){0.f,0.f,0.f,0.f}; w1lo[i] = (f32x4){0.f,0.f,0.f,0.f};
        w2hi[i] = (f32x4){0.f,0.f,0.f,0.f}; w2lo[i] = (f32x4){0.f,0.f,0.f,0.f};
    }
    {
        #pragma unroll 1
        for (int ks = 0; ks < 4; ++ks) {
            const int toff = ((gw * 4 + ks) * 64 + lane) * 8;   // coalesced frag
            f16x8 tah = *(const f16x8*)&FAh[toff];
            f16x8 tal = *(const f16x8*)&FAl[toff];
            f16x8 tvh = *(const f16x8*)&FVh[toff];
            f16x8 tvl = *(const f16x8*)&FVl[toff];
            #pragma unroll
            for (int mi = 0; mi < 4; ++mi) {
                const int base = (16 * (mh + mi) + l15) * XS + ks * 32 + 8 * a4;
                f16x8 xh = *(const f16x8*)&Xh[base];            // aligned b128
                f16x8 xl = *(const f16x8*)&Xl[base];
                w1hi[mi] = MFMA(tah, xh, w1hi[mi]);
                w1lo[mi] = MFMA(tal, xh, w1lo[mi]);
                w1lo[mi] = MFMA(tah, xl, w1lo[mi]);
                w2hi[mi] = MFMA(tvh, xh, w2hi[mi]);
                w2lo[mi] = MFMA(tvl, xh, w2lo[mi]);
                w2lo[mi] = MFMA(tvh, xl, w2lo[mi]);
            }
        }
    }
    __syncthreads();

    // ---- combine + split W into f16 h/l planes (W1 over X region) ----
    {
        const int g = 16 * gw + 4 * a4;
        #pragma unroll
        for (int mi = 0; mi < 4; ++mi) {
            const int m = 16 * (mh + mi) + l15;
            #pragma unroll
            for (int r = 0; r < 4; ++r) {
                float v1 = w1hi[mi][r] + LINV * w1lo[mi][r];
                f16 h1 = (f16)v1;
                float v2 = w2hi[mi][r] + LINV * w2lo[mi][r];
                f16 h2 = (f16)v2;
                W2h[(g + r) * XS + m] = h2;
                W2l[(g + r) * XS + m] = (f16)((v2 - (float)h2) * LSCALE);
                W1h[(g + r) * XS + m] = h1;
                W1l[(g + r) * XS + m] = (f16)((v1 - (float)h1) * LSCALE);
            }
        }
    }
    __syncthreads();

    // ---- pass 2: wave (ft = wv>>1, ghalf = wv&1): C and S paired ----
    const int ft = wv >> 1;
    const int gh = wv & 1;
    f32x4 chi[4], clo[4], shi[4], slo[4];
    #pragma unroll
    for (int i = 0; i < 4; ++i) {
        chi[i] = (f32x4){0.f,0.f,0.f,0.f}; clo[i] = (f32x4){0.f,0.f,0.f,0.f};
        shi[i] = (f32x4){0.f,0.f,0.f,0.f}; slo[i] = (f32x4){0.f,0.f,0.f,0.f};
    }
    {
        #pragma unroll 1
        for (int ks = 0; ks < 4; ++ks) {
            const int toff = ((ft * 4 + ks) * 64 + lane) * 8;   // coalesced frag
            f16x8 tah = *(const f16x8*)&FAh[toff];
            f16x8 tal = *(const f16x8*)&FAl[toff];
            f16x8 tvh = *(const f16x8*)&FVh[toff];
            f16x8 tvl = *(const f16x8*)&FVl[toff];
            #pragma unroll
            for (int gi = 0; gi < 4; ++gi) {
                const int gt = 4 * gh + gi;
                const int base = (16 * gt + l15) * XS + ks * 32 + 8 * a4;
                f16x8 u1h = *(const f16x8*)&W1h[base];
                f16x8 u1l = *(const f16x8*)&W1l[base];
                f16x8 u2h = *(const f16x8*)&W2h[base];
                f16x8 u2l = *(const f16x8*)&W2l[base];
                chi[gi] = MFMA(tah, u1h, chi[gi]);
                clo[gi] = MFMA(tal, u1h, clo[gi]);
                clo[gi] = MFMA(tah, u1l, clo[gi]);
                shi[gi] = MFMA(tvh, u2h, shi[gi]);
                slo[gi] = MFMA(tvl, u2h, slo[gi]);
                slo[gi] = MFMA(tvh, u2l, slo[gi]);
            }
        }
    }

    // ---- epilogue: cosphi (f16, packed into out) + corners, in-register ----
    f16* cph = (f16*)(outbuf + (size_t)img * 16384);
    #pragma unroll
    for (int gi = 0; gi < 4; ++gi) {
        const int g = 16 * (4 * gh + gi) + l15;
        #pragma unroll
        for (int r = 0; r < 4; ++r) {
            const int f = 16 * ft + 4 * a4 + r;
            float Cv = chi[gi][r] + LINV * clo[gi][r];
            float Sv = shi[gi][r] + LINV * slo[gi][r];
            float d = Cv * Cv + Sv * Sv;
            float cp = (d > 0.f) ? Cv * rsqrtf(d) : 1.0f;
            cph[f * 128 + g] = (f16)cp;
            if (gh == 0 && gi == 0) {
                if (ft == 0)      cp1[img * 256 + f * 16 + l15] = Cv;
                else if (ft == 7) cp2[img * 256 + (f - 112) * 16 + l15] = Cv;
            }
        }
    }
}

// ---------------------------------------------------------------------------
// Kernel 2 (fused corner + sparse inverse + final multiply, one block per
// output image (b,o)):
//   corner: od[xy] = 0.5*sum_i( A*(W+Wn) + An*(W-Wn) )   (both corners,
//           fp32, same i-order as before -> bit-identical)
//   R[s1,g] = sum_{f' in F} cas[s1,f'] od[f',g];  y = R*casG/16384
//   out = y * cosphi  (cosphi f16-packed in out's first 32KB per image)
// Kills the od HBM round-trip + one launch; cp L2-shared across 64 o-blocks,
// w L2-shared across 16 b-blocks.
// ---------------------------------------------------------------------------
__global__ __launch_bounds__(256) void k_inv(
    const float* __restrict__ cp1, const float* __restrict__ cp2,
    const float* __restrict__ w1,  const float* __restrict__ w2,
    const float* __restrict__ cas,
    float* __restrict__ out)
{
    __shared__ float odS[32 * 16];
    __shared__ float casF[128 * 33];
    __shared__ float Rs[128 * 17];
    __shared__ float casG[16 * 128];
    __shared__ __align__(16) unsigned short cphS[16384];   // 32KB

    const int img = blockIdx.x;
    const int b = img >> 6, o = img & 63;
    const int t = threadIdx.x;

    // stage f16 cosphi (in-place region of out)
    const uint4* cp16 = (const uint4*)(out + (size_t)img * 16384);
    #pragma unroll
    for (int k = 0; k < 8; ++k) {
        int i = k * 256 + t;
        ((uint4*)cphS)[i] = cp16[i];
    }

    // ---- corner phase (was k_corner), both corners, in-register ----
    {
        const int xx = t >> 4, yy = t & 15;
        const int nx = (16 - xx) & 15, ny = (16 - yy) & 15;
        const int pf = xx * 16 + yy, pn = nx * 16 + ny;
        float acc1 = 0.f, acc2 = 0.f;
        #pragma unroll 4
        for (int i = 0; i < 64; ++i) {
            const int cb = (b * 64 + i) * 256;
            const int wb = (i * 64 + o) * 256;
            float A1  = cp1[cb + pf];
            float A1n = cp1[cb + pn];
            float W1v = w1[wb + pf];
            float W1n = w1[wb + pn];
            acc1 += A1 * (W1v + W1n) + A1n * (W1v - W1n);
            float A2  = cp2[cb + pf];
            float A2n = cp2[cb + pn];
            float W2v = w2[wb + pf];
            float W2n = w2[wb + pn];
            acc2 += A2 * (W2v + W2n) + A2n * (W2v - W2n);
        }
        odS[pf]       = 0.5f * acc1;
        odS[256 + pf] = 0.5f * acc2;
    }

    // ---- stage cas slices ----
    #pragma unroll
    for (int k = 0; k < 16; ++k) {
        int idx = t + k * 256;
        int s = idx >> 5, j = idx & 31;
        int f = (j < 16) ? j : (96 + j);
        casF[s * 33 + j] = cas[s * 128 + f];
    }
    #pragma unroll
    for (int k = 0; k < 8; ++k) {
        int idx = t + k * 256;
        casG[idx] = cas[idx];
    }
    __syncthreads();

    {
        const int s1 = t >> 1, gb = (t & 1) * 8;
        float acc[8];
        #pragma unroll
        for (int l = 0; l < 8; ++l) acc[l] = 0.f;
        #pragma unroll 4
        for (int j = 0; j < 32; ++j) {
            float cf = casF[s1 * 33 + j];
            #pragma unroll
            for (int l = 0; l < 8; ++l)
                acc[l] = fmaf(cf, odS[j * 16 + gb + l], acc[l]);
        }
        #pragma unroll
        for (int l = 0; l < 8; ++l) Rs[s1 * 17 + gb + l] = acc[l];
    }
    __syncthreads();

    const float inv = 1.0f / 16384.0f;
    const int grp = t >> 5, lane = t & 31;
    const int s2 = lane * 4;
    for (int r = 0; r < 16; ++r) {
        const int s1 = grp * 16 + r;
        float4 acc = {0.f, 0.f, 0.f, 0.f};
        #pragma unroll
        for (int g = 0; g < 16; ++g) {
            float rv = Rs[s1 * 17 + g];
            float4 c4 = *(const float4*)&casG[g * 128 + s2];
            acc.x = fmaf(rv, c4.x, acc.x);
            acc.y = fmaf(rv, c4.y, acc.y);
            acc.z = fmaf(rv, c4.z, acc.z);
            acc.w = fmaf(rv, c4.w, acc.w);
        }
        const f16* ph = (const f16*)cphS + s1 * 128 + s2;
        size_t idx = (size_t)img * 16384 + (size_t)s1 * 128 + s2;
        float4 res;
        res.x = acc.x * inv * (float)ph[0];
        res.y = acc.y * inv * (float)ph[1];
        res.z = acc.z * inv * (float)ph[2];
        res.w = acc.w * inv * (float)ph[3];
        *(float4*)&out[idx] = res;
    }
}

// ---------------------------------------------------------------------------
extern "C" void kernel_launch(void* const* d_in, const int* in_sizes, int n_in,
                              void* d_out, int out_size, void* d_ws, size_t ws_size,
                              hipStream_t stream) {
    (void)in_sizes; (void)n_in; (void)out_size; (void)ws_size;
    const float* x  = (const float*)d_in[0];
    const float* w1 = (const float*)d_in[1];
    const float* w2 = (const float*)d_in[2];
    float* out = (float*)d_out;
    float* ws  = (float*)d_ws;

    float* casf = ws;                        // 16384 f32
    f16* FAh = (f16*)(ws + 16384);           // 16384 halfs each, frag-ordered
    f16* FAl = FAh + 16384;
    f16* FVh = FAl + 16384;
    f16* FVl = FVh + 16384;
    float* cp1 = (float*)(FVl + 16384);      // 262144 f32 each
    float* cp2 = cp1 + 262144;               // total ~2.3 MB

    k_cas<<<dim3(128), dim3(128), 0, stream>>>(casf, FAh, FAl, FVh, FVl);
    k_dht<<<dim3(1024), dim3(1024), 0, stream>>>(x, FAh, FAl, FVh, FVl, out, cp1, cp2);
    k_inv<<<dim3(1024), dim3(256), 0, stream>>>(cp1, cp2, w1, w2, casf, out);
}